// Round 3
// baseline (462.739 us; speedup 1.0000x reference)
//
#include <hip/hip_runtime.h>
#include <hip/hip_bf16.h>
#include <stdint.h>

// NearestUpsampling (x2) + 3x3 VALID conv == per-parity 2x2 conv on original x
// == implicit GEMM M=16*63*63=63504, N=(4 par)*(128 Cout), K=128c*4taps=512.
// R7: weight-amplification fix. R4 read the whole 512KB weight array from L2
//     once PER 64-row BLOCK (993x = 508 MB of L2 traffic on the K-loop's
//     critical path). Now BM=128, 1024 threads (16 waves: 2 mh x 2 a x 4 oq),
//     grid=256 persistent blocks x <=2 tiles: 4x less weight L2 traffic
//     (497 tile passes, and mh-pairs share identical wf addresses -> L1 hits).
//     Per-wave K-loop/epilogue byte-identical to verified R4; compiler keeps
//     its own schedule (R6 lesson: no manual pipeline, no setprio).

#define B_    16
#define CIN   128
#define HIN   64
#define WIN   64
#define COUT  128
#define HO    126
#define WO    126
#define M_TOT (B_ * 63 * 63)   // 63504
#define BM    128
#define NTILES ((M_TOT + BM - 1) / BM)   // 497
#define KTILES 16
#define AS_K  520              // bf16 row stride: 1040 B (16B-aligned, bank-spread)

typedef __bf16 bf16;
typedef __bf16 bf16x4 __attribute__((ext_vector_type(4)));
typedef __bf16 bf16x8 __attribute__((ext_vector_type(8)));
typedef float  floatx4 __attribute__((ext_vector_type(4)));

// ---------------------------------------------------------------------------
// Prep: combine 3x3 weights into parity 2x2 weights (bf16).
// Layout: wb[(((kt*4 + par)*128 + o)*32 + k32)], k = kt*32+k32 = c*4 + u*2 + v.
// A wave's (par,o,quad) MFMA fragment is a contiguous 16B run of this array.
// ---------------------------------------------------------------------------
__global__ void prep_weights(const float* __restrict__ w, bf16* __restrict__ wb) {
    int idx = blockIdx.x * 256 + threadIdx.x;
    if (idx >= 4 * KTILES * COUT * 32) return;   // 262144
    int k32 = idx & 31;
    int o   = (idx >> 5) & 127;
    int par = (idx >> 12) & 3;
    int kt  = idx >> 14;
    int k = kt * 32 + k32;
    int c = k >> 2, u = (k >> 1) & 1, v = k & 1;
    int a = par >> 1, bp = par & 1;
    int dy0, dy1, ndy, dx0, dx1, ndx;
    if (u == 0) { if (a == 0) { dy0 = 0; dy1 = 1; ndy = 2; } else { dy0 = 0; dy1 = 0; ndy = 1; } }
    else        { if (a == 0) { dy0 = 2; dy1 = 2; ndy = 1; } else { dy0 = 1; dy1 = 2; ndy = 2; } }
    if (v == 0) { if (bp == 0) { dx0 = 0; dx1 = 1; ndx = 2; } else { dx0 = 0; dx1 = 0; ndx = 1; } }
    else        { if (bp == 0) { dx0 = 2; dx1 = 2; ndx = 1; } else { dx0 = 1; dx1 = 2; ndx = 2; } }
    const float* wp = w + (o * CIN + c) * 9;
    float s = wp[dy0 * 3 + dx0];
    if (ndx == 2) s += wp[dy0 * 3 + dx1];
    if (ndy == 2) { s += wp[dy1 * 3 + dx0]; if (ndx == 2) s += wp[dy1 * 3 + dx1]; }
    wb[idx] = (bf16)s;
}

// ---------------------------------------------------------------------------
// Main kernel. 1024 threads = 16 waves: mh = wid>>3 (m-half), a = (wid>>2)&1
// (row parity), oq = wid&3 (o-quarter). Wave: 32 o x 64 m x both bp via
// mfma(wf, af) -> D[row=o][col=m]. Grid=256, each block loops over <=2 tiles.
// ---------------------------------------------------------------------------
__global__ __launch_bounds__(1024, 4)
void upconv_gemm(const float* __restrict__ x, const bf16* __restrict__ wb,
                 const float* __restrict__ bias, float* __restrict__ out) {
    __shared__ bf16 As[BM * AS_K];   // 133120 B: [m_local][k], whole K

    const int t    = threadIdx.x;
    const int lane = t & 63;
    const int wid  = t >> 6;
    const int mh   = wid >> 3;          // m-half (0/1)
    const int a    = (wid >> 2) & 1;    // output-row parity
    const int oq   = wid & 3;           // o-quarter
    const int quad = lane >> 4;
    const int l15  = lane & 15;
    const int kq   = quad * 8;

    const bf16* wwave = wb + ((size_t)(a * 2) * COUT + oq * 32 + l15) * 32 + kq;

    // bias values are tile-invariant
    float bv[2][4];
    #pragma unroll
    for (int nt = 0; nt < 2; ++nt)
        #pragma unroll
        for (int ri = 0; ri < 4; ++ri)
            bv[nt][ri] = bias[oq * 32 + nt * 16 + quad * 4 + ri];

    for (int tile = blockIdx.x; tile < NTILES; tile += 256) {
        const int m0 = tile * BM;

        __syncthreads();   // As safe to overwrite (no-op cost on first pass)

        // --- stage the ENTIRE A tile (all 512 k) once ---
        // 1024 threads / 128 rows: each row staged by 8 threads, 16 channels each.
        const int ml = t & 127;             // m-row handled by this thread
        const int cg = t >> 7;              // channel-group 0..7
        const int m_mine = m0 + ml;
        const bool mvalid = (m_mine < M_TOT);
        int b_ = 0, p_ = 0, q_ = 0;
        if (mvalid) { b_ = m_mine / 3969; int rr = m_mine - b_ * 3969; p_ = rr / 63; q_ = rr - p_ * 63; }
        const float* xbase = x + ((size_t)(b_ * CIN) * HIN + p_) * WIN + q_;

        #pragma unroll
        for (int cc = 0; cc < 16; ++cc) {
            const int c = cg * 16 + cc;     // channel
            float f00 = 0.f, f01 = 0.f, f10 = 0.f, f11 = 0.f;
            if (mvalid) {
                const float* pa = xbase + (size_t)c * (HIN * WIN);
                f00 = pa[0]; f01 = pa[1]; f10 = pa[WIN]; f11 = pa[WIN + 1];
            }
            bf16x4 v; v[0] = (bf16)f00; v[1] = (bf16)f01; v[2] = (bf16)f10; v[3] = (bf16)f11;
            *(bf16x4*)&As[ml * AS_K + c * 4] = v;   // k = c*4 + tap
        }
        __syncthreads();

        // --- K-loop: no barriers, wf straight from global (L1/L2-resident) ---
        floatx4 acc[2][4][2] = {};   // [bp][mt][nt]

        #pragma unroll
        for (int kt = 0; kt < KTILES; ++kt) {
            bf16x8 af[4], wf[2][2];
            #pragma unroll
            for (int i = 0; i < 4; ++i)
                af[i] = *(const bf16x8*)&As[(mh * 64 + i * 16 + l15) * AS_K + kt * 32 + kq];
            #pragma unroll
            for (int bp = 0; bp < 2; ++bp)
                #pragma unroll
                for (int nt = 0; nt < 2; ++nt)
                    wf[bp][nt] = *(const bf16x8*)(wwave
                        + ((size_t)kt * 4 * COUT + (size_t)bp * COUT + nt * 16) * 32);
            #pragma unroll
            for (int bp = 0; bp < 2; ++bp)
                #pragma unroll
                for (int mt = 0; mt < 4; ++mt)
                    #pragma unroll
                    for (int nt = 0; nt < 2; ++nt)
                        acc[bp][mt][nt] = __builtin_amdgcn_mfma_f32_16x16x32_bf16(
                            wf[bp][nt], af[mt], acc[bp][mt][nt], 0, 0, 0);
        }

        // ---- epilogue: direct coalesced float2 stores (no LDS) ----
        // D layout: col = lane&15 -> m, row = quad*4+ri -> o (within 16-tile).
        #pragma unroll
        for (int mt = 0; mt < 4; ++mt) {
            const int m = m0 + mh * 64 + mt * 16 + l15;
            const bool v = (m < M_TOT);
            int b = 0, p = 0, q = 0;
            if (v) { b = m / 3969; int rr = m - b * 3969; p = rr / 63; q = rr - p * 63; }
            float* base = out + (size_t)b * (COUT * HO * WO) + (size_t)(2 * p + a) * WO + 2 * q;
            #pragma unroll
            for (int nt = 0; nt < 2; ++nt) {
                #pragma unroll
                for (int ri = 0; ri < 4; ++ri) {
                    const int o = oq * 32 + nt * 16 + quad * 4 + ri;
                    if (v) {
                        float2 r = make_float2(acc[0][mt][nt][ri] + bv[nt][ri],
                                               acc[1][mt][nt][ri] + bv[nt][ri]);
                        *(float2*)(base + (size_t)o * (HO * WO)) = r;
                    }
                }
            }
        }
    }
}

extern "C" void kernel_launch(void* const* d_in, const int* in_sizes, int n_in,
                              void* d_out, int out_size, void* d_ws, size_t ws_size,
                              hipStream_t stream) {
    const float* x    = (const float*)d_in[0];
    const float* w    = (const float*)d_in[1];
    const float* bias = (const float*)d_in[2];
    float* out = (float*)d_out;
    bf16* wb = (bf16*)d_ws;   // 512 KB

    prep_weights<<<(4 * KTILES * COUT * 32 + 255) / 256, 256, 0, stream>>>(w, wb);

    upconv_gemm<<<dim3(256), 1024, 0, stream>>>(x, wb, bias, out);
}

// Round 4
// 217.369 us; speedup vs baseline: 2.1288x; 2.1288x over previous
//
#include <hip/hip_runtime.h>
#include <hip/hip_bf16.h>
#include <stdint.h>

// NearestUpsampling (x2) + 3x3 VALID conv == per-parity 2x2 conv on original x
// == implicit GEMM M=16*63*63=63504, N=(4 par)*(128 Cout), K=128c*4taps=512.
// R8: R7's geometry (BM=128, 1024 thr, 16 waves = 2mh x 2a x 4oq) with the
//     spill fixed. R7 died from scratch spill (553MB WRITE): persistent loop +
//     hoisted invariants pushed past the hard 128-reg cap of a 16-wave block.
//     Now: plain grid=497 (no persistence), bias read only in epilogue, all
//     hot indexing in 32-bit. Per-wave stage/K-loop/epilogue byte-equivalent
//     to verified R4 (which fit exactly: 64 arch + 64 acc). Payoff: weight L2
//     traffic halves (497x512KB=254MB vs 993x=508MB) and mh-pairs read
//     identical wf addresses -> L1 hits. LDS 133KB -> 1 block/CU, 16 waves =
//     same 4 waves/SIMD as R4.
// Tripwire: WRITE_SIZE > 200MB in counters => spill recurred => abandon BM128.

#define B_    16
#define CIN   128
#define HIN   64
#define WIN   64
#define COUT  128
#define HO    126
#define WO    126
#define M_TOT (B_ * 63 * 63)   // 63504
#define BM    128
#define NTILES ((M_TOT + BM - 1) / BM)   // 497
#define KTILES 16
#define AS_K  520              // bf16 row stride: 1040 B (16B-aligned, bank-spread)

typedef __bf16 bf16;
typedef __bf16 bf16x4 __attribute__((ext_vector_type(4)));
typedef __bf16 bf16x8 __attribute__((ext_vector_type(8)));
typedef float  floatx4 __attribute__((ext_vector_type(4)));

// ---------------------------------------------------------------------------
// Prep: combine 3x3 weights into parity 2x2 weights (bf16).
// Layout: wb[(((kt*4 + par)*128 + o)*32 + k32)], k = kt*32+k32 = c*4 + u*2 + v.
// A wave's (par,o,quad) MFMA fragment is a contiguous 16B run of this array.
// ---------------------------------------------------------------------------
__global__ void prep_weights(const float* __restrict__ w, bf16* __restrict__ wb) {
    int idx = blockIdx.x * 256 + threadIdx.x;
    if (idx >= 4 * KTILES * COUT * 32) return;   // 262144
    int k32 = idx & 31;
    int o   = (idx >> 5) & 127;
    int par = (idx >> 12) & 3;
    int kt  = idx >> 14;
    int k = kt * 32 + k32;
    int c = k >> 2, u = (k >> 1) & 1, v = k & 1;
    int a = par >> 1, bp = par & 1;
    int dy0, dy1, ndy, dx0, dx1, ndx;
    if (u == 0) { if (a == 0) { dy0 = 0; dy1 = 1; ndy = 2; } else { dy0 = 0; dy1 = 0; ndy = 1; } }
    else        { if (a == 0) { dy0 = 2; dy1 = 2; ndy = 1; } else { dy0 = 1; dy1 = 2; ndy = 2; } }
    if (v == 0) { if (bp == 0) { dx0 = 0; dx1 = 1; ndx = 2; } else { dx0 = 0; dx1 = 0; ndx = 1; } }
    else        { if (bp == 0) { dx0 = 2; dx1 = 2; ndx = 1; } else { dx0 = 1; dx1 = 2; ndx = 2; } }
    const float* wp = w + (o * CIN + c) * 9;
    float s = wp[dy0 * 3 + dx0];
    if (ndx == 2) s += wp[dy0 * 3 + dx1];
    if (ndy == 2) { s += wp[dy1 * 3 + dx0]; if (ndx == 2) s += wp[dy1 * 3 + dx1]; }
    wb[idx] = (bf16)s;
}

// ---------------------------------------------------------------------------
// Main kernel. 1024 threads = 16 waves: mh = wid>>3 (m-half), a = (wid>>2)&1
// (row parity), oq = wid&3 (o-quarter). Wave: 32 o x 64 m x both bp via
// mfma(wf, af) -> D[row=o][col=m].
// ---------------------------------------------------------------------------
__global__ __launch_bounds__(1024, 4)
void upconv_gemm(const float* __restrict__ x, const bf16* __restrict__ wb,
                 const float* __restrict__ bias, float* __restrict__ out) {
    __shared__ bf16 As[BM * AS_K];   // 133120 B: [m_local][k], whole K

    const int t    = threadIdx.x;
    const int lane = t & 63;
    const int wid  = t >> 6;
    const int mh   = wid >> 3;          // m-half (0/1)
    const int a    = (wid >> 2) & 1;    // output-row parity
    const int oq   = wid & 3;           // o-quarter
    const int quad = lane >> 4;
    const int l15  = lane & 15;
    const int kq   = quad * 8;

    const int m0 = blockIdx.x * BM;

    // --- stage the ENTIRE A tile (all 512 k) once ---
    // 1024 threads / 128 rows: each row staged by 8 threads, 16 channels each.
    {
        const int ml = t & 127;             // m-row handled by this thread
        const int cg = t >> 7;              // channel-group 0..7
        const int m_mine = m0 + ml;
        const bool mvalid = (m_mine < M_TOT);
        int b_ = 0, p_ = 0, q_ = 0;
        if (mvalid) { b_ = m_mine / 3969; int rr = m_mine - b_ * 3969; p_ = rr / 63; q_ = rr - p_ * 63; }
        const float* xbase = x + ((b_ * CIN) * HIN + p_) * WIN + q_;   // max idx ~8.4M, int ok

        #pragma unroll
        for (int cc = 0; cc < 16; ++cc) {
            const int c = cg * 16 + cc;     // channel
            float f00 = 0.f, f01 = 0.f, f10 = 0.f, f11 = 0.f;
            if (mvalid) {
                const float* pa = xbase + c * (HIN * WIN);
                f00 = pa[0]; f01 = pa[1]; f10 = pa[WIN]; f11 = pa[WIN + 1];
            }
            bf16x4 v; v[0] = (bf16)f00; v[1] = (bf16)f01; v[2] = (bf16)f10; v[3] = (bf16)f11;
            *(bf16x4*)&As[ml * AS_K + c * 4] = v;   // k = c*4 + tap
        }
    }
    __syncthreads();   // the ONLY barrier

    // --- K-loop: no barriers, wf straight from global (L1/L2-resident) ---
    const bf16* wwave = wb + ((a * 2) * COUT + oq * 32 + l15) * 32 + kq;

    floatx4 acc[2][4][2] = {};   // [bp][mt][nt]

    #pragma unroll
    for (int kt = 0; kt < KTILES; ++kt) {
        bf16x8 af[4], wf[2][2];
        #pragma unroll
        for (int i = 0; i < 4; ++i)
            af[i] = *(const bf16x8*)&As[(mh * 64 + i * 16 + l15) * AS_K + kt * 32 + kq];
        #pragma unroll
        for (int bp = 0; bp < 2; ++bp)
            #pragma unroll
            for (int nt = 0; nt < 2; ++nt)
                wf[bp][nt] = *(const bf16x8*)(wwave
                    + (kt * 4 * COUT + bp * COUT + nt * 16) * 32);   // int offsets
        #pragma unroll
        for (int bp = 0; bp < 2; ++bp)
            #pragma unroll
            for (int mt = 0; mt < 4; ++mt)
                #pragma unroll
                for (int nt = 0; nt < 2; ++nt)
                    acc[bp][mt][nt] = __builtin_amdgcn_mfma_f32_16x16x32_bf16(
                        wf[bp][nt], af[mt], acc[bp][mt][nt], 0, 0, 0);
    }

    // ---- epilogue: direct coalesced float2 stores (no LDS) ----
    // D layout: col = lane&15 -> m, row = quad*4+ri -> o (within 16-tile).
    // bias read HERE (not hoisted) to keep K-loop register pressure minimal.
    float bv[2][4];
    #pragma unroll
    for (int nt = 0; nt < 2; ++nt)
        #pragma unroll
        for (int ri = 0; ri < 4; ++ri)
            bv[nt][ri] = bias[oq * 32 + nt * 16 + quad * 4 + ri];

    #pragma unroll
    for (int mt = 0; mt < 4; ++mt) {
        const int m = m0 + mh * 64 + mt * 16 + l15;
        const bool v = (m < M_TOT);
        int b = 0, p = 0, q = 0;
        if (v) { b = m / 3969; int rr = m - b * 3969; p = rr / 63; q = rr - p * 63; }
        // 32-bit output index: max 16*128*126*126 = 32.5M < 2^31
        const int obase = b * (COUT * HO * WO) + (2 * p + a) * WO + 2 * q;
        #pragma unroll
        for (int nt = 0; nt < 2; ++nt) {
            #pragma unroll
            for (int ri = 0; ri < 4; ++ri) {
                const int o = oq * 32 + nt * 16 + quad * 4 + ri;
                if (v) {
                    float2 r = make_float2(acc[0][mt][nt][ri] + bv[nt][ri],
                                           acc[1][mt][nt][ri] + bv[nt][ri]);
                    *(float2*)(out + obase + o * (HO * WO)) = r;
                }
            }
        }
    }
}

extern "C" void kernel_launch(void* const* d_in, const int* in_sizes, int n_in,
                              void* d_out, int out_size, void* d_ws, size_t ws_size,
                              hipStream_t stream) {
    const float* x    = (const float*)d_in[0];
    const float* w    = (const float*)d_in[1];
    const float* bias = (const float*)d_in[2];
    float* out = (float*)d_out;
    bf16* wb = (bf16*)d_ws;   // 512 KB

    prep_weights<<<(4 * KTILES * COUT * 32 + 255) / 256, 256, 0, stream>>>(w, wb);

    upconv_gemm<<<dim3(NTILES), 1024, 0, stream>>>(x, wb, bias, out);
}

// Round 6
// 214.112 us; speedup vs baseline: 2.1612x; 1.0152x over previous
//
#include <hip/hip_runtime.h>
#include <hip/hip_bf16.h>
#include <stdint.h>

// NearestUpsampling (x2) + 3x3 VALID conv == per-parity 2x2 conv on original x
// == implicit GEMM M=16*63*63=63504, N=(4 par)*(128 Cout), K=128c*4taps=512.
// R10 = R9 with the epilogue race fixed. R9 dumped BOTH row-parities (a=0/1
//     waves) into one 64KB Ld buffer -> collision -> absmax 0.24. Now the
//     epilogue runs in TWO PHASES: phase ap dumps only waves with a==ap, then
//     all 8 waves stream-store the 256 rows of that parity (one contiguous
//     504B row per store instruction). Keeps R9's verified-consistent
//     XOR-swizzled As staging (kills the 2.54M LDS conflict cycles).

#define B_    16
#define CIN   128
#define HIN   64
#define WIN   64
#define COUT  128
#define HO    126
#define WO    126
#define M_TOT (B_ * 63 * 63)   // 63504
#define BM    64
#define KTILES 16
#define AS_K  520              // bf16 row stride: 1040 B (16B-aligned)

typedef __bf16 bf16;
typedef __bf16 bf16x8 __attribute__((ext_vector_type(8)));
typedef float  floatx4 __attribute__((ext_vector_type(4)));

// ---------------------------------------------------------------------------
// Prep: combine 3x3 weights into parity 2x2 weights (bf16).
// Layout: wb[(((kt*4 + par)*128 + o)*32 + k32)], k = kt*32+k32 = c*4 + u*2 + v.
// ---------------------------------------------------------------------------
__global__ void prep_weights(const float* __restrict__ w, bf16* __restrict__ wb) {
    int idx = blockIdx.x * 256 + threadIdx.x;
    if (idx >= 4 * KTILES * COUT * 32) return;   // 262144
    int k32 = idx & 31;
    int o   = (idx >> 5) & 127;
    int par = (idx >> 12) & 3;
    int kt  = idx >> 14;
    int k = kt * 32 + k32;
    int c = k >> 2, u = (k >> 1) & 1, v = k & 1;
    int a = par >> 1, bp = par & 1;
    int dy0, dy1, ndy, dx0, dx1, ndx;
    if (u == 0) { if (a == 0) { dy0 = 0; dy1 = 1; ndy = 2; } else { dy0 = 0; dy1 = 0; ndy = 1; } }
    else        { if (a == 0) { dy0 = 2; dy1 = 2; ndy = 1; } else { dy0 = 1; dy1 = 2; ndy = 2; } }
    if (v == 0) { if (bp == 0) { dx0 = 0; dx1 = 1; ndx = 2; } else { dx0 = 0; dx1 = 0; ndx = 1; } }
    else        { if (bp == 0) { dx0 = 2; dx1 = 2; ndx = 1; } else { dx0 = 1; dx1 = 2; ndx = 2; } }
    const float* wp = w + (o * CIN + c) * 9;
    float s = wp[dy0 * 3 + dx0];
    if (ndx == 2) s += wp[dy0 * 3 + dx1];
    if (ndy == 2) { s += wp[dy1 * 3 + dx0]; if (ndx == 2) s += wp[dy1 * 3 + dx1]; }
    wb[idx] = (bf16)s;
}

// ---------------------------------------------------------------------------
// Main kernel. 512 threads = 8 waves: a = wid>>2 (row parity), oq = wid&3
// (o-quarter). Wave: 32 o x 64 m x both bp via mfma(wf, af) -> D[row=o][col=m].
// ---------------------------------------------------------------------------
__global__ __launch_bounds__(512, 4)
void upconv_gemm(const float* __restrict__ x, const bf16* __restrict__ wb,
                 const float* __restrict__ bias, float* __restrict__ out) {
    __shared__ bf16 As[BM * AS_K];             // 66560 B
    float* Ld = reinterpret_cast<float*>(As);  // epilogue reuse: [o][bp][64] = 65536 B

    const int t    = threadIdx.x;
    const int lane = t & 63;
    const int wid  = t >> 6;
    const int a    = wid >> 2;          // output-row parity
    const int oq   = wid & 3;           // o-quarter
    const int quad = lane >> 4;
    const int l15  = lane & 15;
    const int kq   = quad * 8;

    const int m0 = blockIdx.x * BM;

    // --- stage the ENTIRE A tile (all 512 k), XOR-swizzled 16B granules ---
    {
        const int ml = lane;                // m-row handled by this thread
        const int m_mine = m0 + ml;
        const bool mvalid = (m_mine < M_TOT);
        int b_ = 0, p_ = 0, q_ = 0;
        if (mvalid) { b_ = m_mine / 3969; int rr = m_mine - b_ * 3969; p_ = rr / 63; q_ = rr - p_ * 63; }
        const float* xbase = x + ((b_ * CIN) * HIN + p_) * WIN + q_;
        const int xsw = ml & 7;

        #pragma unroll
        for (int j = 0; j < 8; ++j) {       // granule j: channels c0, c0+1
            const int c0 = wid * 16 + 2 * j;
            float f0[4] = {0.f, 0.f, 0.f, 0.f}, f1[4] = {0.f, 0.f, 0.f, 0.f};
            if (mvalid) {
                const float* pa = xbase + c0 * (HIN * WIN);
                f0[0] = pa[0]; f0[1] = pa[1]; f0[2] = pa[WIN]; f0[3] = pa[WIN + 1];
                const float* pb = pa + (HIN * WIN);
                f1[0] = pb[0]; f1[1] = pb[1]; f1[2] = pb[WIN]; f1[3] = pb[WIN + 1];
            }
            bf16x8 v;
            v[0] = (bf16)f0[0]; v[1] = (bf16)f0[1]; v[2] = (bf16)f0[2]; v[3] = (bf16)f0[3];
            v[4] = (bf16)f1[0]; v[5] = (bf16)f1[1]; v[6] = (bf16)f1[2]; v[7] = (bf16)f1[3];
            const int g = wid * 8 + j;      // data granule index (8 elems = 16 B)
            *(bf16x8*)&As[ml * AS_K + ((g ^ xsw) * 8)] = v;
        }
    }
    __syncthreads();

    // --- K-loop: no barriers, wf straight from global (L2-resident) ---
    const bf16* wwave = wb + ((a * 2) * COUT + oq * 32 + l15) * 32 + kq;

    floatx4 acc[2][4][2] = {};   // [bp][mt][nt]

    #pragma unroll
    for (int kt = 0; kt < KTILES; ++kt) {
        bf16x8 af[4], wf[2][2];
        #pragma unroll
        for (int i = 0; i < 4; ++i) {
            const int row = i * 16 + l15;
            af[i] = *(const bf16x8*)&As[row * AS_K + (((kt * 4 + quad) ^ (row & 7)) * 8)];
        }
        #pragma unroll
        for (int bp = 0; bp < 2; ++bp)
            #pragma unroll
            for (int nt = 0; nt < 2; ++nt)
                wf[bp][nt] = *(const bf16x8*)(wwave
                    + (kt * 4 * COUT + bp * COUT + nt * 16) * 32);
        #pragma unroll
        for (int bp = 0; bp < 2; ++bp)
            #pragma unroll
            for (int mt = 0; mt < 4; ++mt)
                #pragma unroll
                for (int nt = 0; nt < 2; ++nt)
                    acc[bp][mt][nt] = __builtin_amdgcn_mfma_f32_16x16x32_bf16(
                        wf[bp][nt], af[mt], acc[bp][mt][nt], 0, 0, 0);
    }

    // ---- two-phase epilogue: phase ap handles output-row parity ap ----
    const int b_base = m0 / 3969;
    const int rr0 = m0 - b_base * 3969;
    const int p0  = rr0 / 63;
    const int q   = lane;    // q coordinate within output row

    #pragma unroll
    for (int ap = 0; ap < 2; ++ap) {
        __syncthreads();   // ap=0: As reads done; ap=1: phase-0 Ld reads done

        if (a == ap) {
            // dump this parity's acc -> Ld[o][bp][ml ^ (quad<<4)]
            #pragma unroll
            for (int bp = 0; bp < 2; ++bp)
                #pragma unroll
                for (int mt = 0; mt < 4; ++mt)
                    #pragma unroll
                    for (int nt = 0; nt < 2; ++nt)
                        #pragma unroll
                        for (int ri = 0; ri < 4; ++ri) {
                            const int o   = oq * 32 + nt * 16 + quad * 4 + ri;
                            const int mlx = (mt * 16 + l15) ^ (quad << 4);
                            Ld[(o * 2 + bp) * 64 + mlx] = acc[bp][mt][nt][ri];
                        }
        }
        __syncthreads();

        // streaming store: 256 rows (o, pi) of parity ap; 32 rows per wave.
        // One instruction writes a contiguous 504 B output row.
        for (int i = 0; i < 32; ++i) {
            const int rid = wid * 32 + i;      // wave-uniform scalars below
            const int o   = rid >> 1;
            const int pi  = rid & 1;
            int b = b_base, p = p0 + pi;
            if (p > 62) { b += 1; p = 0; }
            if (b >= B_) continue;
            const int base_m = b * 3969 + p * 63;       // m at (b,p,q=0)
            const float bo = bias[o];
            const int m_lane = base_m + q;
            const bool val = (q < 63) && (m_lane >= m0) && (m_lane < m0 + BM) && (m_lane < M_TOT);
            if (val) {
                const int mloc = m_lane - m0;           // 0..63
                const int xsw  = ((o >> 2) & 3) << 4;   // = writer quad << 4
                const float v0 = Ld[(o * 2 + 0) * 64 + (mloc ^ xsw)];
                const float v1 = Ld[(o * 2 + 1) * 64 + (mloc ^ xsw)];
                const int y = 2 * p + ap;
                float* dst = out + b * (COUT * HO * WO) + o * (HO * WO) + y * WO + 2 * q;
                *(float2*)dst = make_float2(v0 + bo, v1 + bo);
            }
        }
    }
}

extern "C" void kernel_launch(void* const* d_in, const int* in_sizes, int n_in,
                              void* d_out, int out_size, void* d_ws, size_t ws_size,
                              hipStream_t stream) {
    const float* x    = (const float*)d_in[0];
    const float* w    = (const float*)d_in[1];
    const float* bias = (const float*)d_in[2];
    float* out = (float*)d_out;
    bf16* wb = (bf16*)d_ws;   // 512 KB

    prep_weights<<<(4 * KTILES * COUT * 32 + 255) / 256, 256, 0, stream>>>(w, wb);

    dim3 grid((M_TOT + BM - 1) / BM);   // 993 blocks
    upconv_gemm<<<grid, 512, 0, stream>>>(x, wb, bias, out);
}